// Round 1
// baseline (278.656 us; speedup 1.0000x reference)
//
#include <hip/hip_runtime.h>
#include <hip/hip_bf16.h>

// Problem constants
#define BB   16384
#define DD   128
#define HH   4
#define EE   8
#define NN   (BB*HH)   // 65536
#define OD   32

// ---------------------------------------------------------------------------
// K1: tok = x@Wq+bq (written to ws), gate = x@Wk+bk -> softmax gating, top-2,
//     routing weights, aux-loss accumulators. 16 batch rows per block.
// ---------------------------------------------------------------------------
__global__ __launch_bounds__(256) void k1_qk_gate(
    const float* __restrict__ x,  const float* __restrict__ Wq, const float* __restrict__ bq,
    const float* __restrict__ Wk, const float* __restrict__ bk, const float* __restrict__ Wg,
    float* __restrict__ tok, int* __restrict__ topi, float* __restrict__ wts,
    float* __restrict__ auxPsum, float* __restrict__ auxCnt)
{
    __shared__ float xsT[128 * 20];     // [kk][r], pitch 20 (16B-aligned, broadcast reads)
    __shared__ float gls[64 * 132];     // [tokrow][d], pitch 132 (conflict-free gating reads)
    __shared__ float lps[EE];
    __shared__ float lcn[EE];

    const int t  = threadIdx.x;
    const int b0 = blockIdx.x * 16;

    if (t < EE) { lps[t] = 0.f; lcn[t] = 0.f; }

    // stage x tile transposed: xsT[kk][r]
    const float4* xf4 = (const float4*)(x + (long)b0 * 128);
    for (int i = t; i < 16 * 32; i += 256) {
        int r = i >> 5, f4 = i & 31;
        float4 v = xf4[r * 32 + f4];
        xsT[(4*f4+0)*20 + r] = v.x;
        xsT[(4*f4+1)*20 + r] = v.y;
        xsT[(4*f4+2)*20 + r] = v.z;
        xsT[(4*f4+3)*20 + r] = v.w;
    }
    __syncthreads();

    // register-blocked GEMM: thread t owns cols {t, t+256} of Wq and of Wk, 16 rows
    float acc0[16], acc1[16], acc2[16], acc3[16];
    #pragma unroll
    for (int i = 0; i < 16; ++i) { acc0[i]=0.f; acc1[i]=0.f; acc2[i]=0.f; acc3[i]=0.f; }

    const float* wq0 = Wq + t;
    const float* wk0 = Wk + t;
    for (int kk = 0; kk < 128; ++kk) {
        float w0 = wq0[kk*512];
        float w1 = wq0[kk*512 + 256];
        float w2 = wk0[kk*512];
        float w3 = wk0[kk*512 + 256];
        const float4* xr = (const float4*)(xsT + kk*20);
        #pragma unroll
        for (int q = 0; q < 4; ++q) {
            float4 xv = xr[q];
            acc0[4*q+0] += xv.x*w0; acc1[4*q+0] += xv.x*w1; acc2[4*q+0] += xv.x*w2; acc3[4*q+0] += xv.x*w3;
            acc0[4*q+1] += xv.y*w0; acc1[4*q+1] += xv.y*w1; acc2[4*q+1] += xv.y*w2; acc3[4*q+1] += xv.y*w3;
            acc0[4*q+2] += xv.z*w0; acc1[4*q+2] += xv.z*w1; acc2[4*q+2] += xv.z*w2; acc3[4*q+2] += xv.z*w3;
            acc0[4*q+3] += xv.w*w0; acc1[4*q+3] += xv.w*w1; acc2[4*q+3] += xv.w*w2; acc3[4*q+3] += xv.w*w3;
        }
    }

    // write tok (q side), stash gate (k side) to LDS
    float bq0 = bq[t], bq1 = bq[t + 256];
    float bk0 = bk[t], bk1 = bk[t + 256];
    int h0 = t >> 7, d0 = t & 127;      // col t
    int h1 = (t + 256) >> 7;            // col t+256; d same (t&127)
    #pragma unroll
    for (int r = 0; r < 16; ++r) {
        long b = b0 + r;
        tok[b*512 + t]        = acc0[r] + bq0;
        tok[b*512 + 256 + t]  = acc1[r] + bq1;
        gls[(r*4 + h0)*132 + d0] = acc2[r] + bk0;
        gls[(r*4 + h1)*132 + d0] = acc3[r] + bk1;
    }
    __syncthreads();

    // gating: 64 token rows x 8 experts; thread -> (tr, e), two rounds
    const int tr0 = t >> 3;
    const int e   = t & 7;
    #pragma unroll
    for (int s = 0; s < 2; ++s) {
        int tr = tr0 + s*32;
        const float* g = gls + tr*132;
        float lg = 0.f;
        for (int d = 0; d < 128; ++d) lg += g[d] * Wg[d*8 + e];

        // softmax over 8 lanes (same tr group)
        float mx = lg;
        for (int m = 1; m < 8; m <<= 1) mx = fmaxf(mx, __shfl_xor(mx, m));
        float p = __expf(lg - mx);
        float sm = p;
        for (int m = 1; m < 8; m <<= 1) sm += __shfl_xor(sm, m);
        float prob = p / sm;

        // top-1 (ties -> lowest index, matching lax.top_k)
        float p1 = prob; int i1 = e;
        for (int m = 1; m < 8; m <<= 1) {
            float po = __shfl_xor(p1, m); int io = __shfl_xor(i1, m);
            if (po > p1 || (po == p1 && io < i1)) { p1 = po; i1 = io; }
        }
        // top-2
        float p2 = (e == i1) ? -1.f : prob; int i2 = e;
        for (int m = 1; m < 8; m <<= 1) {
            float po = __shfl_xor(p2, m); int io = __shfl_xor(i2, m);
            if (po > p2 || (po == p2 && io < i2)) { p2 = po; i2 = io; }
        }

        int n = blockIdx.x * 64 + tr;
        if (e == 0) {
            float inv = 1.f / (p1 + p2);
            topi[2*n]   = i1;  topi[2*n+1] = i2;
            wts[2*n]    = p1 * inv; wts[2*n+1] = p2 * inv;
        }

        // aux accumulators: reduce over the 8 tr-groups of this wave (lanes xor 8/16/32)
        float ps = prob;
        for (int m = 8; m < 64; m <<= 1) ps += __shfl_xor(ps, m);
        float cv = (e == i1) ? 1.f : 0.f;
        for (int m = 8; m < 64; m <<= 1) cv += __shfl_xor(cv, m);
        if ((t & 63) < 8) { atomicAdd(&lps[e], ps); atomicAdd(&lcn[e], cv); }
    }
    __syncthreads();
    if (t < EE) { atomicAdd(&auxPsum[t], lps[t]); atomicAdd(&auxCnt[t], lcn[t]); }
}

// ---------------------------------------------------------------------------
// K2a: bin (token, weight) assignments into per-expert lists
// ---------------------------------------------------------------------------
__global__ __launch_bounds__(256) void k2a_bin(
    const int* __restrict__ topi, const float* __restrict__ wts,
    int* __restrict__ counters, int* __restrict__ listIdx, float* __restrict__ listW)
{
    __shared__ int lcnt[EE];
    __shared__ int lbase[EE];
    int t = threadIdx.x;
    if (t < EE) lcnt[t] = 0;
    __syncthreads();
    int n = blockIdx.x * 256 + t;
    int i0 = topi[2*n], i1 = topi[2*n+1];
    float w0 = wts[2*n], w1 = wts[2*n+1];
    int s0 = atomicAdd(&lcnt[i0], 1);
    int s1 = atomicAdd(&lcnt[i1], 1);
    __syncthreads();
    if (t < EE) lbase[t] = atomicAdd(&counters[t], lcnt[t]);
    __syncthreads();
    int p0 = i0 * NN + lbase[i0] + s0;
    int p1 = i1 * NN + lbase[i1] + s1;
    listIdx[p0] = n; listW[p0] = w0;
    listIdx[p1] = n; listW[p1] = w1;
}

// ---------------------------------------------------------------------------
// K2b: expert-major MLP. 64 tokens of one expert per block.
//      h = relu(tok@W1[e]+b1[e]); o = h@W2[e]+b2[e]; y[n] += w*o (atomic)
// ---------------------------------------------------------------------------
__global__ __launch_bounds__(256) void k2b_expert(
    const float* __restrict__ tok, const float* __restrict__ W1, const float* __restrict__ b1,
    const float* __restrict__ W2, const float* __restrict__ b2,
    const int* __restrict__ counters, const int* __restrict__ listIdx, const float* __restrict__ listW,
    float* __restrict__ y)
{
    __shared__ float tokT[128 * 68];   // [kk][slot], pitch 68 (16B aligned; broadcast b128 reads)
    __shared__ float hL[64 * 129];     // [slot][d], pitch 129 (conflict-free)
    __shared__ int   ids[64];
    __shared__ float wsl[64];

    const int e    = blockIdx.y;
    const int cnt  = counters[e];
    const int base = blockIdx.x * 64;
    if (base >= cnt) return;
    const int t  = threadIdx.x;
    const int nt = min(64, cnt - base);

    if (t < 64) {
        if (t < nt) { ids[t] = listIdx[e*NN + base + t]; wsl[t] = listW[e*NN + base + t]; }
        else        { ids[t] = listIdx[e*NN + base];     wsl[t] = 0.f; }  // pad: weight 0
    }
    __syncthreads();

    // stage 64 token rows transposed (8 threads per row)
    #pragma unroll
    for (int rr = 0; rr < 2; ++rr) {
        int slot = (t >> 3) + rr*32;
        int j = t & 7;
        const float4* src = (const float4*)(tok + (long)ids[slot] * 128);
        #pragma unroll
        for (int m = 0; m < 4; ++m) {
            int f4 = j + m*8;
            float4 v = src[f4];
            tokT[(4*f4+0)*68 + slot] = v.x;
            tokT[(4*f4+1)*68 + slot] = v.y;
            tokT[(4*f4+2)*68 + slot] = v.z;
            tokT[(4*f4+3)*68 + slot] = v.w;
        }
    }
    __syncthreads();

    // h-stage: wave wv handles 16 tokens; lane l owns dims l and l+64
    const int wv = t >> 6;
    const int l  = t & 63;
    float a0[16], a1[16];
    #pragma unroll
    for (int i = 0; i < 16; ++i) { a0[i] = 0.f; a1[i] = 0.f; }
    const float* w1p = W1 + e*16384 + l;
    for (int kk = 0; kk < 128; ++kk) {
        float w0  = w1p[kk*128];
        float w1v = w1p[kk*128 + 64];
        const float4* xr = (const float4*)(tokT + kk*68 + wv*16);
        #pragma unroll
        for (int q = 0; q < 4; ++q) {
            float4 xv = xr[q];
            a0[4*q+0] += xv.x*w0; a1[4*q+0] += xv.x*w1v;
            a0[4*q+1] += xv.y*w0; a1[4*q+1] += xv.y*w1v;
            a0[4*q+2] += xv.z*w0; a1[4*q+2] += xv.z*w1v;
            a0[4*q+3] += xv.w*w0; a1[4*q+3] += xv.w*w1v;
        }
    }
    float bb0 = b1[e*128 + l], bb1 = b1[e*128 + l + 64];
    #pragma unroll
    for (int i = 0; i < 16; ++i) {
        int slot = wv*16 + i;
        hL[slot*129 + l]      = fmaxf(a0[i] + bb0, 0.f);
        hL[slot*129 + l + 64] = fmaxf(a1[i] + bb1, 0.f);
    }
    __syncthreads();

    // o-stage: thread -> (odim, 8 token slots)
    const int od = t & 31;
    const int g  = t >> 5;
    float oa[8];
    #pragma unroll
    for (int j = 0; j < 8; ++j) oa[j] = 0.f;
    const float* w2p = W2 + e*4096 + od;
    for (int d = 0; d < 128; ++d) {
        float w = w2p[d*32];
        #pragma unroll
        for (int j = 0; j < 8; ++j)
            oa[j] += hL[(g*8 + j)*129 + d] * w;
    }
    float b2v = b2[e*32 + od];
    #pragma unroll
    for (int j = 0; j < 8; ++j) {
        int slot = g*8 + j;
        float val = (oa[j] + b2v) * wsl[slot];
        atomicAdd(&y[(long)ids[slot]*32 + od], val);
    }
}

// ---------------------------------------------------------------------------
// K3: out[b] = dot(y_flat[b,:128], Wout[:,0]) + bout
// ---------------------------------------------------------------------------
__global__ __launch_bounds__(256) void k3_head(
    const float* __restrict__ y, const float* __restrict__ Wout,
    const float* __restrict__ bout, float* __restrict__ out)
{
    int t = threadIdx.x;
    int wv = t >> 6, l = t & 63;
    int row = blockIdx.x * 16 + wv*4 + (l >> 4);
    int li = l & 15;
    const float4* yr = (const float4*)(y + (long)row * 128);
    const float4* wr = (const float4*)Wout;
    float4 a = yr[li],     wa = wr[li];
    float4 b = yr[li+16],  wb = wr[li+16];
    float s = a.x*wa.x + a.y*wa.y + a.z*wa.z + a.w*wa.w
            + b.x*wb.x + b.y*wb.y + b.z*wb.z + b.w*wb.w;
    for (int m = 1; m < 16; m <<= 1) s += __shfl_xor(s, m);
    if (li == 0) out[row] = s + bout[0];
}

// ---------------------------------------------------------------------------
// K4: aux loss = E * sum_e (cnt_e/N) * (psum_e/N)
// ---------------------------------------------------------------------------
__global__ void k4_aux(const float* __restrict__ auxPsum, const float* __restrict__ auxCnt,
                       float* __restrict__ out)
{
    if (threadIdx.x == 0) {
        float s = 0.f;
        const float invN = 1.f / (float)NN;
        for (int e = 0; e < EE; ++e) s += (auxCnt[e] * invN) * (auxPsum[e] * invN);
        out[BB] = (float)EE * s;
    }
}

extern "C" void kernel_launch(void* const* d_in, const int* in_sizes, int n_in,
                              void* d_out, int out_size, void* d_ws, size_t ws_size,
                              hipStream_t stream) {
    (void)in_sizes; (void)n_in; (void)out_size; (void)ws_size;
    const float* x    = (const float*)d_in[0];
    const float* Wq   = (const float*)d_in[1];
    const float* bq   = (const float*)d_in[2];
    const float* Wk   = (const float*)d_in[3];
    const float* bk   = (const float*)d_in[4];
    const float* Wg   = (const float*)d_in[5];
    const float* W1   = (const float*)d_in[6];
    const float* b1   = (const float*)d_in[7];
    const float* W2   = (const float*)d_in[8];
    const float* b2   = (const float*)d_in[9];
    const float* Wout = (const float*)d_in[10];
    const float* bout = (const float*)d_in[11];
    float* out = (float*)d_out;

    char* ws = (char*)d_ws;
    float* tok      = (float*)(ws + 0);              // 65536*128*4 = 33,554,432
    float* y        = (float*)(ws + 33554432);       // 65536*32*4  =  8,388,608
    int*   topi     = (int*)  (ws + 41943040);       // 65536*2*4   =    524,288
    float* wts      = (float*)(ws + 42467328);       // 524,288
    int*   listIdx  = (int*)  (ws + 42991616);       // 8*65536*4   =  2,097,152
    float* listW    = (float*)(ws + 45088768);       // 2,097,152
    int*   counters = (int*)  (ws + 47185920);       // 32
    float* auxPsum  = (float*)(ws + 47185952);       // 32
    float* auxCnt   = (float*)(ws + 47185984);       // 32

    hipMemsetAsync(y, 0, 65536*32*4, stream);
    hipMemsetAsync(ws + 47185920, 0, 96, stream);

    k1_qk_gate<<<1024, 256, 0, stream>>>(x, Wq, bq, Wk, bk, Wg, tok, topi, wts, auxPsum, auxCnt);
    k2a_bin<<<256, 256, 0, stream>>>(topi, wts, counters, listIdx, listW);
    k2b_expert<<<dim3(1024, 8), 256, 0, stream>>>(tok, W1, b1, W2, b2, counters, listIdx, listW, y);
    k3_head<<<1024, 256, 0, stream>>>(y, Wout, bout, out);
    k4_aux<<<1, 64, 0, stream>>>(auxPsum, auxCnt, out);
}

// Round 3
// 195.737 us; speedup vs baseline: 1.4236x; 1.4236x over previous
//
#include <hip/hip_runtime.h>
#include <hip/hip_bf16.h>

// Problem constants
#define BB   16384
#define DD   128
#define HH   4
#define EE   8
#define NN   (BB*HH)   // 65536
#define OD   32
#define PT   136       // LDS row pitch in bf16 elems (128 + 8)

typedef __attribute__((ext_vector_type(8))) short short8;
typedef __attribute__((ext_vector_type(4))) short short4v;
typedef __attribute__((ext_vector_type(4))) float f32x4;

// RNE float -> bf16 bits
static __device__ __forceinline__ short f2bf(float v) {
    unsigned int u = __builtin_bit_cast(unsigned int, v);
    u = (u + 0x7FFFu + ((u >> 16) & 1u)) >> 16;
    return (short)u;
}

// ---------------------------------------------------------------------------
// P0/P1/P2: transpose+convert weights to bf16, n-major (A-frag layout)
//   WqT[c][k] = Wq[k][c]   (512*128)
//   W1T[e][h][d] = W1[e][d][h]   (8*128*128)
//   W2T[e][o][d] = W2[e][d][o]   (8*32*128)
// ---------------------------------------------------------------------------
__global__ __launch_bounds__(256) void p0_wqt(const float* __restrict__ Wq, short* __restrict__ WqT) {
    int idx = blockIdx.x * 256 + threadIdx.x;       // 65536
    int c = idx >> 7, k = idx & 127;
    WqT[idx] = f2bf(Wq[k * 512 + c]);
}
__global__ __launch_bounds__(256) void p1_w1t(const float* __restrict__ W1, short* __restrict__ W1T) {
    int idx = blockIdx.x * 256 + threadIdx.x;       // 131072
    int e = idx >> 14, r = idx & 16383, h = r >> 7, d = r & 127;
    W1T[idx] = f2bf(W1[e * 16384 + d * 128 + h]);
}
__global__ __launch_bounds__(256) void p2_w2t(const float* __restrict__ W2, short* __restrict__ W2T) {
    int idx = blockIdx.x * 256 + threadIdx.x;       // 32768
    int e = idx >> 12, r = idx & 4095, o = r >> 7, d = r & 127;
    W2T[idx] = f2bf(W2[e * 4096 + d * 32 + o]);
}

// ---------------------------------------------------------------------------
// K1q: tok = bf16(x @ Wq + bq) via MFMA. Computes D[c][b] (swapped operands):
//   A = WqT rows (c-major), B = x rows staged bf16 in LDS. 32 batch rows/block.
// ---------------------------------------------------------------------------
__global__ __launch_bounds__(256) void k1q_tok(
    const float* __restrict__ x, const short* __restrict__ WqT, const float* __restrict__ bq,
    short* __restrict__ tokb)
{
    __shared__ short xL[32 * PT];
    const int t  = threadIdx.x;
    const int b0 = blockIdx.x * 32;

    // stage 32 rows of x as bf16 (16 elems per thread)
    {
        int slot = t >> 3, seg = t & 7;
        const float4* src = (const float4*)(x + (size_t)(b0 + slot) * 128 + seg * 16);
        float4 v0 = src[0], v1 = src[1], v2 = src[2], v3 = src[3];
        short8 a, b;
        a[0]=f2bf(v0.x); a[1]=f2bf(v0.y); a[2]=f2bf(v0.z); a[3]=f2bf(v0.w);
        a[4]=f2bf(v1.x); a[5]=f2bf(v1.y); a[6]=f2bf(v1.z); a[7]=f2bf(v1.w);
        b[0]=f2bf(v2.x); b[1]=f2bf(v2.y); b[2]=f2bf(v2.z); b[3]=f2bf(v2.w);
        b[4]=f2bf(v3.x); b[5]=f2bf(v3.y); b[6]=f2bf(v3.z); b[7]=f2bf(v3.w);
        *(short8*)(xL + slot * PT + seg * 16)     = a;
        *(short8*)(xL + slot * PT + seg * 16 + 8) = b;
    }
    __syncthreads();

    const int wv   = t >> 6;          // c-slice [wv*128, wv*128+128)
    const int lane = t & 63;
    const int l16  = lane & 15;
    const int quad = lane >> 4;

    f32x4 acc[8][2];
    #pragma unroll
    for (int ml = 0; ml < 8; ++ml)
        #pragma unroll
        for (int nl = 0; nl < 2; ++nl)
            acc[ml][nl] = (f32x4){0.f, 0.f, 0.f, 0.f};

    short8 bf[2][4];
    #pragma unroll
    for (int nl = 0; nl < 2; ++nl)
        #pragma unroll
        for (int ks = 0; ks < 4; ++ks)
            bf[nl][ks] = *(const short8*)(xL + (nl*16 + l16) * PT + ks*32 + quad*8);

    #pragma unroll
    for (int ks = 0; ks < 4; ++ks) {
        short8 af[8];
        #pragma unroll
        for (int ml = 0; ml < 8; ++ml)
            af[ml] = *(const short8*)(WqT + ((size_t)(wv*128 + ml*16 + l16)) * 128 + ks*32 + quad*8);
        #pragma unroll
        for (int ml = 0; ml < 8; ++ml)
            #pragma unroll
            for (int nl = 0; nl < 2; ++nl)
                acc[ml][nl] = __builtin_amdgcn_mfma_f32_16x16x32_bf16(af[ml], bf[nl][ks], acc[ml][nl], 0, 0, 0);
    }

    // epilogue: D[c][b] -> tokb[b*512 + c], 4 consecutive c per store
    #pragma unroll
    for (int ml = 0; ml < 8; ++ml) {
        int c0 = wv*128 + ml*16 + quad*4;
        f32x4 bqv = *(const f32x4*)(bq + c0);
        #pragma unroll
        for (int nl = 0; nl < 2; ++nl) {
            int b = b0 + nl*16 + l16;
            short4v hv;
            #pragma unroll
            for (int r = 0; r < 4; ++r) hv[r] = f2bf(acc[ml][nl][r] + bqv[r]);
            *(short4v*)(tokb + (size_t)b * 512 + c0) = hv;
        }
    }
}

// ---------------------------------------------------------------------------
// K1g: gate = x@Wk+bk (fp32) -> softmax gating, top-2, routing weights,
//      aux + assignment-count accumulators. 16 batch rows per block.
// ---------------------------------------------------------------------------
__global__ __launch_bounds__(256) void k1_gate(
    const float* __restrict__ x, const float* __restrict__ Wk, const float* __restrict__ bk,
    const float* __restrict__ Wg,
    int* __restrict__ topi, float* __restrict__ wts,
    float* __restrict__ auxPsum, float* __restrict__ auxCnt, int* __restrict__ assignCnt)
{
    __shared__ float xsT[128 * 20];
    __shared__ float gls[64 * 132];
    __shared__ float lps[EE];
    __shared__ float lcn[EE];
    __shared__ int   lasg[EE];

    const int t  = threadIdx.x;
    const int b0 = blockIdx.x * 16;

    if (t < EE) { lps[t] = 0.f; lcn[t] = 0.f; lasg[t] = 0; }

    const float4* xf4 = (const float4*)(x + (long)b0 * 128);
    for (int i = t; i < 16 * 32; i += 256) {
        int r = i >> 5, f4 = i & 31;
        float4 v = xf4[r * 32 + f4];
        xsT[(4*f4+0)*20 + r] = v.x;
        xsT[(4*f4+1)*20 + r] = v.y;
        xsT[(4*f4+2)*20 + r] = v.z;
        xsT[(4*f4+3)*20 + r] = v.w;
    }
    __syncthreads();

    float acc2[16], acc3[16];
    #pragma unroll
    for (int i = 0; i < 16; ++i) { acc2[i]=0.f; acc3[i]=0.f; }

    const float* wk0 = Wk + t;
    for (int kk = 0; kk < 128; ++kk) {
        float w2 = wk0[kk*512];
        float w3 = wk0[kk*512 + 256];
        const float4* xr = (const float4*)(xsT + kk*20);
        #pragma unroll
        for (int q = 0; q < 4; ++q) {
            float4 xv = xr[q];
            acc2[4*q+0] += xv.x*w2; acc3[4*q+0] += xv.x*w3;
            acc2[4*q+1] += xv.y*w2; acc3[4*q+1] += xv.y*w3;
            acc2[4*q+2] += xv.z*w2; acc3[4*q+2] += xv.z*w3;
            acc2[4*q+3] += xv.w*w2; acc3[4*q+3] += xv.w*w3;
        }
    }

    float bk0 = bk[t], bk1 = bk[t + 256];
    int h0 = t >> 7, d0 = t & 127;
    int h1 = (t + 256) >> 7;
    #pragma unroll
    for (int r = 0; r < 16; ++r) {
        gls[(r*4 + h0)*132 + d0] = acc2[r] + bk0;
        gls[(r*4 + h1)*132 + d0] = acc3[r] + bk1;
    }
    __syncthreads();

    const int tr0 = t >> 3;
    const int e   = t & 7;
    #pragma unroll
    for (int s = 0; s < 2; ++s) {
        int tr = tr0 + s*32;
        const float* g = gls + tr*132;
        float lg = 0.f;
        for (int d = 0; d < 128; ++d) lg += g[d] * Wg[d*8 + e];

        float mx = lg;
        for (int m = 1; m < 8; m <<= 1) mx = fmaxf(mx, __shfl_xor(mx, m));
        float p = __expf(lg - mx);
        float sm = p;
        for (int m = 1; m < 8; m <<= 1) sm += __shfl_xor(sm, m);
        float prob = p / sm;

        float p1 = prob; int i1 = e;
        for (int m = 1; m < 8; m <<= 1) {
            float po = __shfl_xor(p1, m); int io = __shfl_xor(i1, m);
            if (po > p1 || (po == p1 && io < i1)) { p1 = po; i1 = io; }
        }
        float p2 = (e == i1) ? -1.f : prob; int i2 = e;
        for (int m = 1; m < 8; m <<= 1) {
            float po = __shfl_xor(p2, m); int io = __shfl_xor(i2, m);
            if (po > p2 || (po == p2 && io < i2)) { p2 = po; i2 = io; }
        }

        int n = blockIdx.x * 64 + tr;
        if (e == 0) {
            float inv = 1.f / (p1 + p2);
            topi[2*n]   = i1;  topi[2*n+1] = i2;
            wts[2*n]    = p1 * inv; wts[2*n+1] = p2 * inv;
            atomicAdd(&lasg[i1], 1);
            atomicAdd(&lasg[i2], 1);
        }

        float ps = prob;
        for (int m = 8; m < 64; m <<= 1) ps += __shfl_xor(ps, m);
        float cv = (e == i1) ? 1.f : 0.f;
        for (int m = 8; m < 64; m <<= 1) cv += __shfl_xor(cv, m);
        if ((t & 63) < 8) { atomicAdd(&lps[e], ps); atomicAdd(&lcn[e], cv); }
    }
    __syncthreads();
    if (t < EE) {
        atomicAdd(&auxPsum[t], lps[t]);
        atomicAdd(&auxCnt[t], lcn[t]);
        atomicAdd(&assignCnt[t], lasg[t]);
    }
}

// ---------------------------------------------------------------------------
// K2s: exclusive scan of assignment counts, padded to 64-multiples so no
//      64-token tile straddles an expert boundary. Compact total <= 131584.
// ---------------------------------------------------------------------------
__global__ void k2s_scan(const int* __restrict__ assignCnt,
                         int* __restrict__ bases, int* __restrict__ cursors) {
    if (threadIdx.x == 0) {
        int b = 0;
        for (int e = 0; e < EE; ++e) {
            bases[e] = b; cursors[e] = b;
            b += (assignCnt[e] + 63) & ~63;
        }
    }
}

// ---------------------------------------------------------------------------
// K2a: bin assignments into compact per-expert lists; record positions
// ---------------------------------------------------------------------------
__global__ __launch_bounds__(256) void k2a_bin(
    const int* __restrict__ topi,
    int* __restrict__ cursors, int* __restrict__ listIdx, int* __restrict__ posIdx)
{
    __shared__ int lcnt[EE];
    __shared__ int lbase[EE];
    int t = threadIdx.x;
    if (t < EE) lcnt[t] = 0;
    __syncthreads();
    int n = blockIdx.x * 256 + t;
    int i0 = topi[2*n], i1 = topi[2*n+1];
    int s0 = atomicAdd(&lcnt[i0], 1);
    int s1 = atomicAdd(&lcnt[i1], 1);
    __syncthreads();
    if (t < EE) lbase[t] = atomicAdd(&cursors[t], lcnt[t]);
    __syncthreads();
    int p0 = lbase[i0] + s0;
    int p1 = lbase[i1] + s1;
    listIdx[p0] = n; posIdx[2*n]   = p0;
    listIdx[p1] = n; posIdx[2*n+1] = p1;
}

// ---------------------------------------------------------------------------
// K2b: expert MLP via bf16 MFMA. 64 tokens of one expert per block.
//   GEMM1': h[hid][tok] = W1T . tok^T  (M=128,N=64,K=128), relu+bias -> hL
//   GEMM2': o[od][tok]  = W2T . h^T    (M=32, N=64,K=128), +bias -> oList
// ---------------------------------------------------------------------------
__global__ __launch_bounds__(256) void k2b_expert(
    const short* __restrict__ tokb, const short* __restrict__ W1T,
    const float* __restrict__ b1, const short* __restrict__ W2T, const float* __restrict__ b2,
    const int* __restrict__ assignCnt, const int* __restrict__ bases,
    const int* __restrict__ listIdx, float* __restrict__ oList)
{
    __shared__ short tokL[64 * PT];
    __shared__ short hL[64 * PT];
    __shared__ int   ids[64];

    const int e    = blockIdx.y;
    const int cnt  = assignCnt[e];
    const int off  = blockIdx.x * 64;
    if (off >= cnt) return;
    const int sb   = bases[e] + off;   // compact segment base for this tile
    const int t    = threadIdx.x;
    const int nt   = min(64, cnt - off);

    if (t < 64) ids[t] = listIdx[sb + min(t, nt - 1)];
    __syncthreads();

    #pragma unroll
    for (int r = 0; r < 4; ++r) {
        int i = t + r * 256;
        int slot = i >> 4, seg = i & 15;
        short8 v = *(const short8*)(tokb + (size_t)ids[slot] * 128 + seg * 8);
        *(short8*)(tokL + slot * PT + seg * 8) = v;
    }
    __syncthreads();

    const int wv   = t >> 6;
    const int lane = t & 63;
    const int l16  = lane & 15;
    const int quad = lane >> 4;

    // ---- GEMM1': wave owns hid slice [wv*32, wv*32+32) ----
    f32x4 acc[2][4];
    #pragma unroll
    for (int ml = 0; ml < 2; ++ml)
        #pragma unroll
        for (int nl = 0; nl < 4; ++nl)
            acc[ml][nl] = (f32x4){0.f, 0.f, 0.f, 0.f};

    short8 af[2][4];
    #pragma unroll
    for (int ml = 0; ml < 2; ++ml)
        #pragma unroll
        for (int ks = 0; ks < 4; ++ks)
            af[ml][ks] = *(const short8*)(W1T + ((size_t)(e*128 + wv*32 + ml*16 + l16)) * 128 + ks*32 + quad*8);

    short8 bf[4][4];
    #pragma unroll
    for (int nl = 0; nl < 4; ++nl)
        #pragma unroll
        for (int ks = 0; ks < 4; ++ks)
            bf[nl][ks] = *(const short8*)(tokL + (nl*16 + l16) * PT + ks*32 + quad*8);

    #pragma unroll
    for (int ks = 0; ks < 4; ++ks)
        #pragma unroll
        for (int ml = 0; ml < 2; ++ml)
            #pragma unroll
            for (int nl = 0; nl < 4; ++nl)
                acc[ml][nl] = __builtin_amdgcn_mfma_f32_16x16x32_bf16(af[ml][ks], bf[nl][ks], acc[ml][nl], 0, 0, 0);

    #pragma unroll
    for (int ml = 0; ml < 2; ++ml) {
        int hid0 = wv*32 + ml*16 + quad*4;
        f32x4 b1v = *(const f32x4*)(b1 + e*128 + hid0);
        #pragma unroll
        for (int nl = 0; nl < 4; ++nl) {
            short4v hv;
            #pragma unroll
            for (int r = 0; r < 4; ++r) {
                float v = acc[ml][nl][r] + b1v[r];
                hv[r] = f2bf(fmaxf(v, 0.f));
            }
            *(short4v*)(hL + (nl*16 + l16) * PT + hid0) = hv;
        }
    }
    __syncthreads();

    // ---- GEMM2': wave owns tok tile nl = wv ----
    f32x4 acc2[2];
    acc2[0] = (f32x4){0.f, 0.f, 0.f, 0.f};
    acc2[1] = (f32x4){0.f, 0.f, 0.f, 0.f};

    short8 af2[2][4];
    #pragma unroll
    for (int ml = 0; ml < 2; ++ml)
        #pragma unroll
        for (int ks = 0; ks < 4; ++ks)
            af2[ml][ks] = *(const short8*)(W2T + ((size_t)(e*32 + ml*16 + l16)) * 128 + ks*32 + quad*8);

    short8 bf2[4];
    #pragma unroll
    for (int ks = 0; ks < 4; ++ks)
        bf2[ks] = *(const short8*)(hL + (wv*16 + l16) * PT + ks*32 + quad*8);

    #pragma unroll
    for (int ks = 0; ks < 4; ++ks)
        #pragma unroll
        for (int ml = 0; ml < 2; ++ml)
            acc2[ml] = __builtin_amdgcn_mfma_f32_16x16x32_bf16(af2[ml][ks], bf2[ks], acc2[ml], 0, 0, 0);

    const int tok = wv*16 + l16;
    const size_t p = (size_t)sb + tok;
    #pragma unroll
    for (int ml = 0; ml < 2; ++ml) {
        int od0 = ml*16 + quad*4;
        f32x4 b2v = *(const f32x4*)(b2 + e*32 + od0);
        f32x4 o;
        #pragma unroll
        for (int r = 0; r < 4; ++r) o[r] = acc2[ml][r] + b2v[r];
        *(f32x4*)(oList + p*32 + od0) = o;
    }
}

// ---------------------------------------------------------------------------
// K3: gather both expert outputs per token, weight, fuse head GEMV.
// ---------------------------------------------------------------------------
__global__ __launch_bounds__(256) void k3_head(
    const float* __restrict__ oList, const int* __restrict__ posIdx, const float* __restrict__ wts,
    const float* __restrict__ Wout, const float* __restrict__ bout, float* __restrict__ out)
{
    int t = threadIdx.x;
    int b = blockIdx.x * 8 + (t >> 5);
    int l = t & 31;
    int h = l >> 3, seg = l & 7;
    int n = b * 4 + h;

    float4 wseg = ((const float4*)Wout)[h * 8 + seg];
    float val = 0.f;
    #pragma unroll
    for (int s = 0; s < 2; ++s) {
        int   p = posIdx[2*n + s];
        float w = wts[2*n + s];
        float4 o = ((const float4*)oList)[(size_t)p * 8 + seg];
        val += w * (o.x*wseg.x + o.y*wseg.y + o.z*wseg.z + o.w*wseg.w);
    }
    #pragma unroll
    for (int m = 1; m < 32; m <<= 1) val += __shfl_xor(val, m);
    if (l == 0) out[b] = val + bout[0];
}

// ---------------------------------------------------------------------------
// K4: aux loss
// ---------------------------------------------------------------------------
__global__ void k4_aux(const float* __restrict__ auxPsum, const float* __restrict__ auxCnt,
                       float* __restrict__ out)
{
    if (threadIdx.x == 0) {
        float s = 0.f;
        const float invN = 1.f / (float)NN;
        for (int e = 0; e < EE; ++e) s += (auxCnt[e] * invN) * (auxPsum[e] * invN);
        out[BB] = (float)EE * s;
    }
}

extern "C" void kernel_launch(void* const* d_in, const int* in_sizes, int n_in,
                              void* d_out, int out_size, void* d_ws, size_t ws_size,
                              hipStream_t stream) {
    (void)in_sizes; (void)n_in; (void)out_size; (void)ws_size;
    const float* x    = (const float*)d_in[0];
    const float* Wq   = (const float*)d_in[1];
    const float* bq   = (const float*)d_in[2];
    const float* Wk   = (const float*)d_in[3];
    const float* bk   = (const float*)d_in[4];
    const float* Wg   = (const float*)d_in[5];
    const float* W1   = (const float*)d_in[6];
    const float* b1   = (const float*)d_in[7];
    const float* W2   = (const float*)d_in[8];
    const float* b2   = (const float*)d_in[9];
    const float* Wout = (const float*)d_in[10];
    const float* bout = (const float*)d_in[11];
    float* out = (float*)d_out;

    char* ws = (char*)d_ws;
    short* tokb     = (short*)(ws + 0);              // 16,777,216
    float* oList    = (float*)(ws + 16777216);       // 131584*32*4 = 16,842,752
    int*   topi     = (int*)  (ws + 33619968);       //    524,288
    float* wts      = (float*)(ws + 34144256);       //    524,288
    int*   posIdx   = (int*)  (ws + 34668544);       //    524,288
    int*   listIdx  = (int*)  (ws + 35192832);       //    526,336
    short* WqT      = (short*)(ws + 35719168);       //    131,072
    short* W1T      = (short*)(ws + 35850240);       //    262,144
    short* W2T      = (short*)(ws + 36112384);       //     65,536
    int*   assignCnt= (int*)  (ws + 36177920);       //         32
    float* auxPsum  = (float*)(ws + 36177952);       //         32
    float* auxCnt   = (float*)(ws + 36177984);       //         32
    int*   bases    = (int*)  (ws + 36178016);       //         32
    int*   cursors  = (int*)  (ws + 36178048);       //         32

    hipMemsetAsync(ws + 36177920, 0, 160, stream);

    p0_wqt<<<256, 256, 0, stream>>>(Wq, WqT);
    p1_w1t<<<512, 256, 0, stream>>>(W1, W1T);
    p2_w2t<<<128, 256, 0, stream>>>(W2, W2T);
    k1q_tok<<<512, 256, 0, stream>>>(x, WqT, bq, tokb);
    k1_gate<<<1024, 256, 0, stream>>>(x, Wk, bk, Wg, topi, wts, auxPsum, auxCnt, assignCnt);
    k2s_scan<<<1, 64, 0, stream>>>(assignCnt, bases, cursors);
    k2a_bin<<<256, 256, 0, stream>>>(topi, cursors, listIdx, posIdx);
    k2b_expert<<<dim3(1024, 8), 256, 0, stream>>>(tokb, W1T, b1, W2T, b2, assignCnt, bases, listIdx, oList);
    k3_head<<<2048, 256, 0, stream>>>(oList, posIdx, wts, Wout, bout, out);
    k4_aux<<<1, 64, 0, stream>>>(auxPsum, auxCnt, out);
}

// Round 4
// 157.404 us; speedup vs baseline: 1.7703x; 1.2435x over previous
//
#include <hip/hip_runtime.h>
#include <hip/hip_bf16.h>

// Problem constants
#define BB   16384
#define DD   128
#define HH   4
#define EE   8
#define NN   (BB*HH)   // 65536
#define OD   32
#define PT   136       // LDS row pitch in bf16 elems (128 + 8)

typedef __attribute__((ext_vector_type(8))) short short8;
typedef __attribute__((ext_vector_type(4))) short short4v;
typedef __attribute__((ext_vector_type(4))) float f32x4;

// RNE float -> bf16 bits
static __device__ __forceinline__ short f2bf(float v) {
    unsigned int u = __builtin_bit_cast(unsigned int, v);
    u = (u + 0x7FFFu + ((u >> 16) & 1u)) >> 16;
    return (short)u;
}

// ---------------------------------------------------------------------------
// PREP (fused): weight transposes to bf16 n-major + gate collapse precompute
//   WqT[c][k]    = Wq[k][c]                       (512*128)      blocks [0,256)
//   W1T[e][h][d] = W1[e][d][h]                    (8*128*128)    blocks [256,768)
//   W2T[e][o][d] = W2[e][d][o]                    (8*32*128)     blocks [768,896)
//   Wkg[k][h*8+e]= sum_d Wk[k][h*128+d]*Wg[d][e]  (128*32)       blocks [896,912)
//   bkg[h*8+e]   = sum_d bk[h*128+d]*Wg[d][e]     (32)           block 912
// ---------------------------------------------------------------------------
__global__ __launch_bounds__(256) void prep(
    const float* __restrict__ Wq, const float* __restrict__ Wk, const float* __restrict__ Wg,
    const float* __restrict__ bk, const float* __restrict__ W1, const float* __restrict__ W2,
    short* __restrict__ WqT, short* __restrict__ W1T, short* __restrict__ W2T,
    float* __restrict__ Wkg, float* __restrict__ bkg)
{
    int idx = blockIdx.x * 256 + threadIdx.x;
    if (idx < 65536) {
        int c = idx >> 7, k = idx & 127;
        WqT[idx] = f2bf(Wq[k * 512 + c]);
    } else if (idx < 196608) {
        int j = idx - 65536;
        int e = j >> 14, r = j & 16383, hh = r >> 7, d = r & 127;
        W1T[j] = f2bf(W1[e * 16384 + d * 128 + hh]);
    } else if (idx < 229376) {
        int j = idx - 196608;
        int e = j >> 12, r = j & 4095, o = r >> 7, d = r & 127;
        W2T[j] = f2bf(W2[e * 4096 + d * 32 + o]);
    } else if (idx < 233472) {
        int j = idx - 229376;
        int k = j >> 5, col = j & 31, hh = col >> 3, e = col & 7;
        float s = 0.f;
        for (int d = 0; d < 128; ++d) s += Wk[k * 512 + hh * 128 + d] * Wg[d * 8 + e];
        Wkg[k * 32 + col] = s;
    } else if (idx < 233504) {
        int j = idx - 233472;
        int hh = j >> 3, e = j & 7;
        float s = 0.f;
        for (int d = 0; d < 128; ++d) s += bk[hh * 128 + d] * Wg[d * 8 + e];
        bkg[j] = s;
    }
}

// ---------------------------------------------------------------------------
// K1q: tok = bf16(x @ Wq + bq) via MFMA. Computes D[c][b] (swapped operands).
// ---------------------------------------------------------------------------
__global__ __launch_bounds__(256) void k1q_tok(
    const float* __restrict__ x, const short* __restrict__ WqT, const float* __restrict__ bq,
    short* __restrict__ tokb)
{
    __shared__ short xL[32 * PT];
    const int t  = threadIdx.x;
    const int b0 = blockIdx.x * 32;

    {
        int slot = t >> 3, seg = t & 7;
        const float4* src = (const float4*)(x + (size_t)(b0 + slot) * 128 + seg * 16);
        float4 v0 = src[0], v1 = src[1], v2 = src[2], v3 = src[3];
        short8 a, b;
        a[0]=f2bf(v0.x); a[1]=f2bf(v0.y); a[2]=f2bf(v0.z); a[3]=f2bf(v0.w);
        a[4]=f2bf(v1.x); a[5]=f2bf(v1.y); a[6]=f2bf(v1.z); a[7]=f2bf(v1.w);
        b[0]=f2bf(v2.x); b[1]=f2bf(v2.y); b[2]=f2bf(v2.z); b[3]=f2bf(v2.w);
        b[4]=f2bf(v3.x); b[5]=f2bf(v3.y); b[6]=f2bf(v3.z); b[7]=f2bf(v3.w);
        *(short8*)(xL + slot * PT + seg * 16)     = a;
        *(short8*)(xL + slot * PT + seg * 16 + 8) = b;
    }
    __syncthreads();

    const int wv   = t >> 6;
    const int lane = t & 63;
    const int l16  = lane & 15;
    const int quad = lane >> 4;

    f32x4 acc[8][2];
    #pragma unroll
    for (int ml = 0; ml < 8; ++ml)
        #pragma unroll
        for (int nl = 0; nl < 2; ++nl)
            acc[ml][nl] = (f32x4){0.f, 0.f, 0.f, 0.f};

    short8 bf[2][4];
    #pragma unroll
    for (int nl = 0; nl < 2; ++nl)
        #pragma unroll
        for (int ks = 0; ks < 4; ++ks)
            bf[nl][ks] = *(const short8*)(xL + (nl*16 + l16) * PT + ks*32 + quad*8);

    #pragma unroll
    for (int ks = 0; ks < 4; ++ks) {
        short8 af[8];
        #pragma unroll
        for (int ml = 0; ml < 8; ++ml)
            af[ml] = *(const short8*)(WqT + ((size_t)(wv*128 + ml*16 + l16)) * 128 + ks*32 + quad*8);
        #pragma unroll
        for (int ml = 0; ml < 8; ++ml)
            #pragma unroll
            for (int nl = 0; nl < 2; ++nl)
                acc[ml][nl] = __builtin_amdgcn_mfma_f32_16x16x32_bf16(af[ml], bf[nl][ks], acc[ml][nl], 0, 0, 0);
    }

    #pragma unroll
    for (int ml = 0; ml < 8; ++ml) {
        int c0 = wv*128 + ml*16 + quad*4;
        f32x4 bqv = *(const f32x4*)(bq + c0);
        #pragma unroll
        for (int nl = 0; nl < 2; ++nl) {
            int b = b0 + nl*16 + l16;
            short4v hv;
            #pragma unroll
            for (int r = 0; r < 4; ++r) hv[r] = f2bf(acc[ml][nl][r] + bqv[r]);
            *(short4v*)(tokb + (size_t)b * 512 + c0) = hv;
        }
    }
}

// ---------------------------------------------------------------------------
// K1g: gating via collapsed Wkg. Thread <-> token; wave is h-uniform so Wkg
//      loads are scalar (K$ broadcast). Softmax/top-2 in registers.
//      Per-block partials (no global atomics): blkPart[blk][0:8]=prob sums,
//      [8:16]=top1 counts, [16:24]=assign counts.
// ---------------------------------------------------------------------------
__global__ __launch_bounds__(256) void k1_gate(
    const float* __restrict__ x, const float* __restrict__ Wkg, const float* __restrict__ bkg,
    int* __restrict__ topi, float* __restrict__ wts, float* __restrict__ blkPart)
{
    __shared__ float xL[64 * 129];
    __shared__ float lps[EE];
    __shared__ float lcn[EE];
    __shared__ float lasg[EE];

    const int t  = threadIdx.x;
    const int b0 = blockIdx.x * 64;

    if (t < EE) { lps[t] = 0.f; lcn[t] = 0.f; lasg[t] = 0.f; }

    for (int i = t; i < 2048; i += 256) {
        int r = i >> 5, c = i & 31;
        float4 v = ((const float4*)(x + (size_t)(b0 + r) * 128))[c];
        float* dst = xL + r * 129 + c * 4;
        dst[0] = v.x; dst[1] = v.y; dst[2] = v.z; dst[3] = v.w;
    }
    __syncthreads();

    const int h  = __builtin_amdgcn_readfirstlane(t >> 6);   // wave-uniform head
    const int lb = t & 63;

    const f32x4* wkg4 = (const f32x4*)Wkg;
    f32x4 a0 = ((const f32x4*)bkg)[h * 2];
    f32x4 a1 = ((const f32x4*)bkg)[h * 2 + 1];

    const float* xrow = xL + lb * 129;
    #pragma unroll 4
    for (int k = 0; k < 128; ++k) {
        float xv = xrow[k];
        f32x4 w0 = wkg4[k * 8 + h * 2];
        f32x4 w1 = wkg4[k * 8 + h * 2 + 1];
        a0 += w0 * xv;
        a1 += w1 * xv;
    }

    float l[8] = {a0[0], a0[1], a0[2], a0[3], a1[0], a1[1], a1[2], a1[3]};
    float mx = l[0];
    #pragma unroll
    for (int e = 1; e < 8; ++e) mx = fmaxf(mx, l[e]);
    float p[8]; float sm = 0.f;
    #pragma unroll
    for (int e = 0; e < 8; ++e) { p[e] = __expf(l[e] - mx); sm += p[e]; }
    float isin = 1.f / sm;
    #pragma unroll
    for (int e = 0; e < 8; ++e) p[e] *= isin;

    int i1 = 0; float p1 = p[0];
    #pragma unroll
    for (int e = 1; e < 8; ++e) if (p[e] > p1) { p1 = p[e]; i1 = e; }
    int i2 = (i1 == 0) ? 1 : 0; float p2 = p[i2];
    #pragma unroll
    for (int e = 0; e < 8; ++e) if (e != i1 && p[e] > p2) { p2 = p[e]; i2 = e; }

    int n = (b0 + lb) * 4 + h;
    float rinv = 1.f / (p1 + p2);
    topi[2*n]   = i1;        topi[2*n+1] = i2;
    wts[2*n]    = p1 * rinv; wts[2*n+1]  = p2 * rinv;

    #pragma unroll
    for (int e = 0; e < 8; ++e) {
        float v = p[e];
        #pragma unroll
        for (int m2 = 1; m2 < 64; m2 <<= 1) v += __shfl_xor(v, m2);
        unsigned long long m1b = __ballot(i1 == e);
        unsigned long long m2b = __ballot(i2 == e);
        if (lb == 0) {
            float c1 = (float)__popcll(m1b);
            atomicAdd(&lps[e], v);
            atomicAdd(&lcn[e], c1);
            atomicAdd(&lasg[e], c1 + (float)__popcll(m2b));
        }
    }
    __syncthreads();
    if (t < EE) {
        float* bp = blkPart + blockIdx.x * 32;
        bp[t]      = lps[t];
        bp[8 + t]  = lcn[t];
        bp[16 + t] = lasg[t];
    }
}

// ---------------------------------------------------------------------------
// K2s: reduce per-block partials -> aux loss (out[BB]), assignment counts,
//      64-padded exclusive-scan bases + cursors.
// ---------------------------------------------------------------------------
__global__ __launch_bounds__(256) void k2s_scan(
    const float* __restrict__ blkPart,
    int* __restrict__ bases, int* __restrict__ cursors, int* __restrict__ assignCnt,
    float* __restrict__ out)
{
    __shared__ float red[8][32];
    __shared__ float fin[24];
    const int t = threadIdx.x;
    const int chunk = t >> 5, s = t & 31;
    float v = 0.f;
    for (int i = 0; i < 32; ++i) v += blkPart[(chunk * 32 + i) * 32 + s];
    red[chunk][s] = v;
    __syncthreads();
    if (t < 24) {
        float sum = 0.f;
        #pragma unroll
        for (int c = 0; c < 8; ++c) sum += red[c][t];
        fin[t] = sum;
    }
    __syncthreads();
    if (t == 0) {
        int b = 0;
        float aux = 0.f;
        const float invN = 1.f / (float)NN;
        for (int e = 0; e < EE; ++e) {
            aux += (fin[8 + e] * invN) * (fin[e] * invN);
            int a = (int)(fin[16 + e] + 0.5f);
            assignCnt[e] = a;
            bases[e] = b; cursors[e] = b;
            b += (a + 63) & ~63;
        }
        out[BB] = (float)EE * aux;
    }
}

// ---------------------------------------------------------------------------
// K2a: bin assignments into compact per-expert lists; record positions
// ---------------------------------------------------------------------------
__global__ __launch_bounds__(256) void k2a_bin(
    const int* __restrict__ topi,
    int* __restrict__ cursors, int* __restrict__ listIdx, int* __restrict__ posIdx)
{
    __shared__ int lcnt[EE];
    __shared__ int lbase[EE];
    int t = threadIdx.x;
    if (t < EE) lcnt[t] = 0;
    __syncthreads();
    int n = blockIdx.x * 256 + t;
    int i0 = topi[2*n], i1 = topi[2*n+1];
    int s0 = atomicAdd(&lcnt[i0], 1);
    int s1 = atomicAdd(&lcnt[i1], 1);
    __syncthreads();
    if (t < EE) lbase[t] = atomicAdd(&cursors[t], lcnt[t]);
    __syncthreads();
    int p0 = lbase[i0] + s0;
    int p1 = lbase[i1] + s1;
    listIdx[p0] = n; posIdx[2*n]   = p0;
    listIdx[p1] = n; posIdx[2*n+1] = p1;
}

// ---------------------------------------------------------------------------
// K2b: expert MLP via bf16 MFMA. 64 tokens of one expert per block.
// ---------------------------------------------------------------------------
__global__ __launch_bounds__(256) void k2b_expert(
    const short* __restrict__ tokb, const short* __restrict__ W1T,
    const float* __restrict__ b1, const short* __restrict__ W2T, const float* __restrict__ b2,
    const int* __restrict__ assignCnt, const int* __restrict__ bases,
    const int* __restrict__ listIdx, float* __restrict__ oList)
{
    __shared__ short tokL[64 * PT];
    __shared__ short hL[64 * PT];
    __shared__ int   ids[64];

    const int e    = blockIdx.y;
    const int cnt  = assignCnt[e];
    const int off  = blockIdx.x * 64;
    if (off >= cnt) return;
    const int sb   = bases[e] + off;
    const int t    = threadIdx.x;
    const int nt   = min(64, cnt - off);

    if (t < 64) ids[t] = listIdx[sb + min(t, nt - 1)];
    __syncthreads();

    #pragma unroll
    for (int r = 0; r < 4; ++r) {
        int i = t + r * 256;
        int slot = i >> 4, seg = i & 15;
        short8 v = *(const short8*)(tokb + (size_t)ids[slot] * 128 + seg * 8);
        *(short8*)(tokL + slot * PT + seg * 8) = v;
    }
    __syncthreads();

    const int wv   = t >> 6;
    const int lane = t & 63;
    const int l16  = lane & 15;
    const int quad = lane >> 4;

    f32x4 acc[2][4];
    #pragma unroll
    for (int ml = 0; ml < 2; ++ml)
        #pragma unroll
        for (int nl = 0; nl < 4; ++nl)
            acc[ml][nl] = (f32x4){0.f, 0.f, 0.f, 0.f};

    short8 af[2][4];
    #pragma unroll
    for (int ml = 0; ml < 2; ++ml)
        #pragma unroll
        for (int ks = 0; ks < 4; ++ks)
            af[ml][ks] = *(const short8*)(W1T + ((size_t)(e*128 + wv*32 + ml*16 + l16)) * 128 + ks*32 + quad*8);

    short8 bf[4][4];
    #pragma unroll
    for (int nl = 0; nl < 4; ++nl)
        #pragma unroll
        for (int ks = 0; ks < 4; ++ks)
            bf[nl][ks] = *(const short8*)(tokL + (nl*16 + l16) * PT + ks*32 + quad*8);

    #pragma unroll
    for (int ks = 0; ks < 4; ++ks)
        #pragma unroll
        for (int ml = 0; ml < 2; ++ml)
            #pragma unroll
            for (int nl = 0; nl < 4; ++nl)
                acc[ml][nl] = __builtin_amdgcn_mfma_f32_16x16x32_bf16(af[ml][ks], bf[nl][ks], acc[ml][nl], 0, 0, 0);

    #pragma unroll
    for (int ml = 0; ml < 2; ++ml) {
        int hid0 = wv*32 + ml*16 + quad*4;
        f32x4 b1v = *(const f32x4*)(b1 + e*128 + hid0);
        #pragma unroll
        for (int nl = 0; nl < 4; ++nl) {
            short4v hv;
            #pragma unroll
            for (int r = 0; r < 4; ++r) {
                float v = acc[ml][nl][r] + b1v[r];
                hv[r] = f2bf(fmaxf(v, 0.f));
            }
            *(short4v*)(hL + (nl*16 + l16) * PT + hid0) = hv;
        }
    }
    __syncthreads();

    f32x4 acc2[2];
    acc2[0] = (f32x4){0.f, 0.f, 0.f, 0.f};
    acc2[1] = (f32x4){0.f, 0.f, 0.f, 0.f};

    short8 af2[2][4];
    #pragma unroll
    for (int ml = 0; ml < 2; ++ml)
        #pragma unroll
        for (int ks = 0; ks < 4; ++ks)
            af2[ml][ks] = *(const short8*)(W2T + ((size_t)(e*32 + ml*16 + l16)) * 128 + ks*32 + quad*8);

    short8 bf2[4];
    #pragma unroll
    for (int ks = 0; ks < 4; ++ks)
        bf2[ks] = *(const short8*)(hL + (wv*16 + l16) * PT + ks*32 + quad*8);

    #pragma unroll
    for (int ks = 0; ks < 4; ++ks)
        #pragma unroll
        for (int ml = 0; ml < 2; ++ml)
            acc2[ml] = __builtin_amdgcn_mfma_f32_16x16x32_bf16(af2[ml][ks], bf2[ks], acc2[ml], 0, 0, 0);

    const int tok = wv*16 + l16;
    const size_t pp = (size_t)sb + tok;
    #pragma unroll
    for (int ml = 0; ml < 2; ++ml) {
        int od0 = ml*16 + quad*4;
        f32x4 b2v = *(const f32x4*)(b2 + e*32 + od0);
        f32x4 o;
        #pragma unroll
        for (int r = 0; r < 4; ++r) o[r] = acc2[ml][r] + b2v[r];
        *(f32x4*)(oList + pp*32 + od0) = o;
    }
}

// ---------------------------------------------------------------------------
// K3: gather both expert outputs per token, weight, fuse head GEMV.
// ---------------------------------------------------------------------------
__global__ __launch_bounds__(256) void k3_head(
    const float* __restrict__ oList, const int* __restrict__ posIdx, const float* __restrict__ wts,
    const float* __restrict__ Wout, const float* __restrict__ bout, float* __restrict__ out)
{
    int t = threadIdx.x;
    int b = blockIdx.x * 8 + (t >> 5);
    int l = t & 31;
    int h = l >> 3, seg = l & 7;
    int n = b * 4 + h;

    float4 wseg = ((const float4*)Wout)[h * 8 + seg];
    float val = 0.f;
    #pragma unroll
    for (int s = 0; s < 2; ++s) {
        int   p = posIdx[2*n + s];
        float w = wts[2*n + s];
        float4 o = ((const float4*)oList)[(size_t)p * 8 + seg];
        val += w * (o.x*wseg.x + o.y*wseg.y + o.z*wseg.z + o.w*wseg.w);
    }
    #pragma unroll
    for (int m = 1; m < 32; m <<= 1) val += __shfl_xor(val, m);
    if (l == 0) out[b] = val + bout[0];
}

extern "C" void kernel_launch(void* const* d_in, const int* in_sizes, int n_in,
                              void* d_out, int out_size, void* d_ws, size_t ws_size,
                              hipStream_t stream) {
    (void)in_sizes; (void)n_in; (void)out_size; (void)ws_size;
    const float* x    = (const float*)d_in[0];
    const float* Wq   = (const float*)d_in[1];
    const float* bq   = (const float*)d_in[2];
    const float* Wk   = (const float*)d_in[3];
    const float* bk   = (const float*)d_in[4];
    const float* Wg   = (const float*)d_in[5];
    const float* W1   = (const float*)d_in[6];
    const float* b1   = (const float*)d_in[7];
    const float* W2   = (const float*)d_in[8];
    const float* b2   = (const float*)d_in[9];
    const float* Wout = (const float*)d_in[10];
    const float* bout = (const float*)d_in[11];
    float* out = (float*)d_out;

    char* ws = (char*)d_ws;
    short* tokb     = (short*)(ws + 0);              // 16,777,216
    float* oList    = (float*)(ws + 16777216);       // 131584*32*4 = 16,842,752
    int*   topi     = (int*)  (ws + 33619968);       //    524,288
    float* wts      = (float*)(ws + 34144256);       //    524,288
    int*   posIdx   = (int*)  (ws + 34668544);       //    524,288
    int*   listIdx  = (int*)  (ws + 35192832);       //    526,336
    short* WqT      = (short*)(ws + 35719168);       //    131,072
    short* W1T      = (short*)(ws + 35850240);       //    262,144
    short* W2T      = (short*)(ws + 36112384);       //     65,536
    float* Wkg      = (float*)(ws + 36177920);       //     16,384
    float* bkg      = (float*)(ws + 36194304);       //        128
    float* blkPart  = (float*)(ws + 36194432);       //     32,768
    int*   bases    = (int*)  (ws + 36227200);       //         32
    int*   cursors  = (int*)  (ws + 36227232);       //         32
    int*   assignCnt= (int*)  (ws + 36227264);       //         32

    prep<<<913, 256, 0, stream>>>(Wq, Wk, Wg, bk, W1, W2, WqT, W1T, W2T, Wkg, bkg);
    k1q_tok<<<512, 256, 0, stream>>>(x, WqT, bq, tokb);
    k1_gate<<<256, 256, 0, stream>>>(x, Wkg, bkg, topi, wts, blkPart);
    k2s_scan<<<1, 256, 0, stream>>>(blkPart, bases, cursors, assignCnt, out);
    k2a_bin<<<256, 256, 0, stream>>>(topi, cursors, listIdx, posIdx);
    k2b_expert<<<dim3(1024, 8), 256, 0, stream>>>(tokb, W1T, b1, W2T, b2, assignCnt, bases, listIdx, oList);
    k3_head<<<2048, 256, 0, stream>>>(oList, posIdx, wts, Wout, bout, out);
}

// Round 5
// 138.627 us; speedup vs baseline: 2.0101x; 1.1355x over previous
//
#include <hip/hip_runtime.h>
#include <hip/hip_bf16.h>

// Problem constants
#define BB   16384
#define DD   128
#define HH   4
#define EE   8
#define NN   (BB*HH)   // 65536
#define OD   32
#define PT   136       // LDS row pitch in bf16 elems (128 + 8)

typedef __attribute__((ext_vector_type(8))) short short8;
typedef __attribute__((ext_vector_type(4))) short short4v;
typedef __attribute__((ext_vector_type(4))) float f32x4;

// RNE float -> bf16 bits
static __device__ __forceinline__ short f2bf(float v) {
    unsigned int u = __builtin_bit_cast(unsigned int, v);
    u = (u + 0x7FFFu + ((u >> 16) & 1u)) >> 16;
    return (short)u;
}

// ---------------------------------------------------------------------------
// PREP (fused): weights -> bf16 in MFMA *fragment order* (coalesced A-loads),
// gate collapse precompute, out[] = bout init.
// Fragment order: for a 16(m)x32(k) A-tile, lane=(quad<<4)|l16 holds
//   m = l16, k = quad*8 + j (j=0..7), stored as 8 contiguous shorts per lane.
//   flat idx = ((tile*4 + ks)*64 + lane)*8 + j,  k = ks*32 + quad*8 + j
// Segments (thread idx ranges):
//   [0,65536)        WqF : tile ct=idx>>11 (32 c-tiles), src Wq[k][ct*16+l16]
//   [65536,196608)   W1F : e=..>>14, mt=(..>>11)&7, src W1[e][k][mt*16+l16]
//   [196608,229376)  W2F : e=..>>12, mt=(..>>11)&1, src W2[e][k][mt*16+l16]
//   [229376,233472)  Wkg[k][h*8+e] = sum_d Wk[k][h*128+d]*Wg[d][e]
//   [233472,233504)  bkg[h*8+e]    = sum_d bk[h*128+d]*Wg[d][e]
//   [233504,249888)  out[b] = bout[0]
// ---------------------------------------------------------------------------
__global__ __launch_bounds__(256) void prep(
    const float* __restrict__ Wq, const float* __restrict__ Wk, const float* __restrict__ Wg,
    const float* __restrict__ bk, const float* __restrict__ W1, const float* __restrict__ W2,
    const float* __restrict__ bout,
    short* __restrict__ WqF, short* __restrict__ W1F, short* __restrict__ W2F,
    float* __restrict__ Wkg, float* __restrict__ bkg, float* __restrict__ out)
{
    int idx = blockIdx.x * 256 + threadIdx.x;
    if (idx < 65536) {
        int j = idx & 7, lane = (idx >> 3) & 63, ks = (idx >> 9) & 3, ct = idx >> 11;
        int l16 = lane & 15, quad = lane >> 4;
        int c = ct * 16 + l16, k = ks * 32 + quad * 8 + j;
        WqF[idx] = f2bf(Wq[k * 512 + c]);
    } else if (idx < 196608) {
        int r = idx - 65536;
        int j = r & 7, lane = (r >> 3) & 63, ks = (r >> 9) & 3, mt = (r >> 11) & 7, e = r >> 14;
        int l16 = lane & 15, quad = lane >> 4;
        int m = mt * 16 + l16, k = ks * 32 + quad * 8 + j;
        W1F[r] = f2bf(W1[e * 16384 + k * 128 + m]);
    } else if (idx < 229376) {
        int r = idx - 196608;
        int j = r & 7, lane = (r >> 3) & 63, ks = (r >> 9) & 3, mt = (r >> 11) & 1, e = r >> 12;
        int l16 = lane & 15, quad = lane >> 4;
        int m = mt * 16 + l16, k = ks * 32 + quad * 8 + j;
        W2F[r] = f2bf(W2[e * 4096 + k * 32 + m]);
    } else if (idx < 233472) {
        int r = idx - 229376;
        int k = r >> 5, col = r & 31, hh = col >> 3, e = col & 7;
        float s = 0.f;
        for (int d = 0; d < 128; ++d) s += Wk[k * 512 + hh * 128 + d] * Wg[d * 8 + e];
        Wkg[k * 32 + col] = s;
    } else if (idx < 233504) {
        int r = idx - 233472;
        int hh = r >> 3, e = r & 7;
        float s = 0.f;
        for (int d = 0; d < 128; ++d) s += bk[hh * 128 + d] * Wg[d * 8 + e];
        bkg[r] = s;
    } else if (idx < 249888) {
        out[idx - 233504] = bout[0];
    }
}

// ---------------------------------------------------------------------------
// K1q: tok = bf16(x @ Wq + bq) via MFMA, D[c][b] (swapped operands).
//      A-frags from fragment-ordered WqF (coalesced 16B/lane loads).
// ---------------------------------------------------------------------------
__global__ __launch_bounds__(256) void k1q_tok(
    const float* __restrict__ x, const short* __restrict__ WqF, const float* __restrict__ bq,
    short* __restrict__ tokb)
{
    __shared__ short xL[32 * PT];
    const int t  = threadIdx.x;
    const int b0 = blockIdx.x * 32;

    {
        int slot = t >> 3, seg = t & 7;
        const float4* src = (const float4*)(x + (size_t)(b0 + slot) * 128 + seg * 16);
        float4 v0 = src[0], v1 = src[1], v2 = src[2], v3 = src[3];
        short8 a, b;
        a[0]=f2bf(v0.x); a[1]=f2bf(v0.y); a[2]=f2bf(v0.z); a[3]=f2bf(v0.w);
        a[4]=f2bf(v1.x); a[5]=f2bf(v1.y); a[6]=f2bf(v1.z); a[7]=f2bf(v1.w);
        b[0]=f2bf(v2.x); b[1]=f2bf(v2.y); b[2]=f2bf(v2.z); b[3]=f2bf(v2.w);
        b[4]=f2bf(v3.x); b[5]=f2bf(v3.y); b[6]=f2bf(v3.z); b[7]=f2bf(v3.w);
        *(short8*)(xL + slot * PT + seg * 16)     = a;
        *(short8*)(xL + slot * PT + seg * 16 + 8) = b;
    }
    __syncthreads();

    const int wv   = t >> 6;
    const int lane = t & 63;
    const int l16  = lane & 15;
    const int quad = lane >> 4;

    f32x4 acc[8][2];
    #pragma unroll
    for (int ml = 0; ml < 8; ++ml)
        #pragma unroll
        for (int nl = 0; nl < 2; ++nl)
            acc[ml][nl] = (f32x4){0.f, 0.f, 0.f, 0.f};

    short8 bf[2][4];
    #pragma unroll
    for (int nl = 0; nl < 2; ++nl)
        #pragma unroll
        for (int ks = 0; ks < 4; ++ks)
            bf[nl][ks] = *(const short8*)(xL + (nl*16 + l16) * PT + ks*32 + quad*8);

    #pragma unroll
    for (int ks = 0; ks < 4; ++ks) {
        short8 af[8];
        #pragma unroll
        for (int ml = 0; ml < 8; ++ml)
            af[ml] = *(const short8*)(WqF + ((size_t)(((wv*8 + ml)*4 + ks)*64 + lane)) * 8);
        #pragma unroll
        for (int ml = 0; ml < 8; ++ml)
            #pragma unroll
            for (int nl = 0; nl < 2; ++nl)
                acc[ml][nl] = __builtin_amdgcn_mfma_f32_16x16x32_bf16(af[ml], bf[nl][ks], acc[ml][nl], 0, 0, 0);
    }

    #pragma unroll
    for (int ml = 0; ml < 8; ++ml) {
        int c0 = wv*128 + ml*16 + quad*4;
        f32x4 bqv = *(const f32x4*)(bq + c0);
        #pragma unroll
        for (int nl = 0; nl < 2; ++nl) {
            int b = b0 + nl*16 + l16;
            short4v hv;
            #pragma unroll
            for (int r = 0; r < 4; ++r) hv[r] = f2bf(acc[ml][nl][r] + bqv[r]);
            *(short4v*)(tokb + (size_t)b * 512 + c0) = hv;
        }
    }
}

// ---------------------------------------------------------------------------
// K1g: gating via collapsed Wkg (scalar K$ loads), softmax/top-2 in registers,
//      per-block partials (no global atomics).
// ---------------------------------------------------------------------------
__global__ __launch_bounds__(256) void k1_gate(
    const float* __restrict__ x, const float* __restrict__ Wkg, const float* __restrict__ bkg,
    int* __restrict__ topi, float* __restrict__ wts, float* __restrict__ blkPart)
{
    __shared__ float xL[64 * 129];
    __shared__ float lps[EE];
    __shared__ float lcn[EE];
    __shared__ float lasg[EE];

    const int t  = threadIdx.x;
    const int b0 = blockIdx.x * 64;

    if (t < EE) { lps[t] = 0.f; lcn[t] = 0.f; lasg[t] = 0.f; }

    for (int i = t; i < 2048; i += 256) {
        int r = i >> 5, c = i & 31;
        float4 v = ((const float4*)(x + (size_t)(b0 + r) * 128))[c];
        float* dst = xL + r * 129 + c * 4;
        dst[0] = v.x; dst[1] = v.y; dst[2] = v.z; dst[3] = v.w;
    }
    __syncthreads();

    const int h  = __builtin_amdgcn_readfirstlane(t >> 6);
    const int lb = t & 63;

    const f32x4* wkg4 = (const f32x4*)Wkg;
    f32x4 a0 = ((const f32x4*)bkg)[h * 2];
    f32x4 a1 = ((const f32x4*)bkg)[h * 2 + 1];

    const float* xrow = xL + lb * 129;
    #pragma unroll 4
    for (int k = 0; k < 128; ++k) {
        float xv = xrow[k];
        f32x4 w0 = wkg4[k * 8 + h * 2];
        f32x4 w1 = wkg4[k * 8 + h * 2 + 1];
        a0 += w0 * xv;
        a1 += w1 * xv;
    }

    float l[8] = {a0[0], a0[1], a0[2], a0[3], a1[0], a1[1], a1[2], a1[3]};
    float mx = l[0];
    #pragma unroll
    for (int e = 1; e < 8; ++e) mx = fmaxf(mx, l[e]);
    float p[8]; float sm = 0.f;
    #pragma unroll
    for (int e = 0; e < 8; ++e) { p[e] = __expf(l[e] - mx); sm += p[e]; }
    float isin = 1.f / sm;
    #pragma unroll
    for (int e = 0; e < 8; ++e) p[e] *= isin;

    int i1 = 0; float p1 = p[0];
    #pragma unroll
    for (int e = 1; e < 8; ++e) if (p[e] > p1) { p1 = p[e]; i1 = e; }
    int i2 = (i1 == 0) ? 1 : 0; float p2 = p[i2];
    #pragma unroll
    for (int e = 0; e < 8; ++e) if (e != i1 && p[e] > p2) { p2 = p[e]; i2 = e; }

    int n = (b0 + lb) * 4 + h;
    float rinv = 1.f / (p1 + p2);
    topi[2*n]   = i1;        topi[2*n+1] = i2;
    wts[2*n]    = p1 * rinv; wts[2*n+1]  = p2 * rinv;

    #pragma unroll
    for (int e = 0; e < 8; ++e) {
        float v = p[e];
        #pragma unroll
        for (int m2 = 1; m2 < 64; m2 <<= 1) v += __shfl_xor(v, m2);
        unsigned long long m1b = __ballot(i1 == e);
        unsigned long long m2b = __ballot(i2 == e);
        if (lb == 0) {
            float c1 = (float)__popcll(m1b);
            atomicAdd(&lps[e], v);
            atomicAdd(&lcn[e], c1);
            atomicAdd(&lasg[e], c1 + (float)__popcll(m2b));
        }
    }
    __syncthreads();
    if (t < EE) {
        float* bp = blkPart + blockIdx.x * 32;
        bp[t]      = lps[t];
        bp[8 + t]  = lcn[t];
        bp[16 + t] = lasg[t];
    }
}

// ---------------------------------------------------------------------------
// K2s: reduce partials -> aux loss (out[BB]), 64-padded bases + cursors.
// ---------------------------------------------------------------------------
__global__ __launch_bounds__(256) void k2s_scan(
    const float* __restrict__ blkPart,
    int* __restrict__ bases, int* __restrict__ cursors, int* __restrict__ assignCnt,
    float* __restrict__ out)
{
    __shared__ float red[8][32];
    __shared__ float fin[24];
    const int t = threadIdx.x;
    const int chunk = t >> 5, s = t & 31;
    float v = 0.f;
    for (int i = 0; i < 32; ++i) v += blkPart[(chunk * 32 + i) * 32 + s];
    red[chunk][s] = v;
    __syncthreads();
    if (t < 24) {
        float sum = 0.f;
        #pragma unroll
        for (int c = 0; c < 8; ++c) sum += red[c][t];
        fin[t] = sum;
    }
    __syncthreads();
    if (t == 0) {
        int b = 0;
        float aux = 0.f;
        const float invN = 1.f / (float)NN;
        for (int e = 0; e < EE; ++e) {
            aux += (fin[8 + e] * invN) * (fin[e] * invN);
            int a = (int)(fin[16 + e] + 0.5f);
            assignCnt[e] = a;
            bases[e] = b; cursors[e] = b;
            b += (a + 63) & ~63;
        }
        out[BB] = (float)EE * aux;
    }
}

// ---------------------------------------------------------------------------
// K2a: bin assignments into compact per-expert lists; value = 2*n + rank
// ---------------------------------------------------------------------------
__global__ __launch_bounds__(256) void k2a_bin(
    const int* __restrict__ topi,
    int* __restrict__ cursors, int* __restrict__ listIdx)
{
    __shared__ int lcnt[EE];
    __shared__ int lbase[EE];
    int t = threadIdx.x;
    if (t < EE) lcnt[t] = 0;
    __syncthreads();
    int n = blockIdx.x * 256 + t;
    int i0 = topi[2*n], i1 = topi[2*n+1];
    int s0 = atomicAdd(&lcnt[i0], 1);
    int s1 = atomicAdd(&lcnt[i1], 1);
    __syncthreads();
    if (t < EE) lbase[t] = atomicAdd(&cursors[t], lcnt[t]);
    __syncthreads();
    listIdx[lbase[i0] + s0] = 2*n;
    listIdx[lbase[i1] + s1] = 2*n + 1;
}

// ---------------------------------------------------------------------------
// K2b: expert MLP via bf16 MFMA + fused head. 64 tokens of one expert/block.
//   GEMM1': h[hid][tok] = W1F . tok^T  (128x64x128) relu+bias -> hL
//   GEMM2': o[od][tok]  = W2F . h^T    (32x64x128)  +bias
//   head:   out[n>>2] += w * dot(o, Wout[h*32..h*32+32))   (atomic, 64/block)
// ---------------------------------------------------------------------------
__global__ __launch_bounds__(256) void k2b_expert(
    const short* __restrict__ tokb, const short* __restrict__ W1F,
    const float* __restrict__ b1, const short* __restrict__ W2F, const float* __restrict__ b2,
    const int* __restrict__ assignCnt, const int* __restrict__ bases,
    const int* __restrict__ listIdx, const float* __restrict__ wts,
    const float* __restrict__ Wout, float* __restrict__ out)
{
    __shared__ short tokL[64 * PT];
    __shared__ short hL[64 * PT];
    __shared__ int   ids[64];
    __shared__ float wsl[64];
    __shared__ float WoutL[128];

    const int e    = blockIdx.y;
    const int cnt  = assignCnt[e];
    const int off  = blockIdx.x * 64;
    if (off >= cnt) return;
    const int sb   = bases[e] + off;
    const int t    = threadIdx.x;
    const int nt   = min(64, cnt - off);

    if (t < 64) {
        int a = listIdx[sb + min(t, nt - 1)];
        ids[t] = a >> 1;
        wsl[t] = (t < nt) ? wts[a] : 0.f;
    }
    if (t >= 128 && t < 256) WoutL[t - 128] = Wout[t - 128];
    __syncthreads();

    #pragma unroll
    for (int r = 0; r < 4; ++r) {
        int i = t + r * 256;
        int slot = i >> 4, seg = i & 15;
        short8 v = *(const short8*)(tokb + (size_t)ids[slot] * 128 + seg * 8);
        *(short8*)(tokL + slot * PT + seg * 8) = v;
    }
    __syncthreads();

    const int wv   = t >> 6;
    const int lane = t & 63;
    const int l16  = lane & 15;
    const int quad = lane >> 4;

    // ---- GEMM1' ----
    f32x4 acc[2][4];
    #pragma unroll
    for (int ml = 0; ml < 2; ++ml)
        #pragma unroll
        for (int nl = 0; nl < 4; ++nl)
            acc[ml][nl] = (f32x4){0.f, 0.f, 0.f, 0.f};

    short8 af[2][4];
    #pragma unroll
    for (int ml = 0; ml < 2; ++ml)
        #pragma unroll
        for (int ks = 0; ks < 4; ++ks)
            af[ml][ks] = *(const short8*)(W1F + ((size_t)(((e*8 + wv*2 + ml)*4 + ks)*64 + lane)) * 8);

    short8 bf[4][4];
    #pragma unroll
    for (int nl = 0; nl < 4; ++nl)
        #pragma unroll
        for (int ks = 0; ks < 4; ++ks)
            bf[nl][ks] = *(const short8*)(tokL + (nl*16 + l16) * PT + ks*32 + quad*8);

    #pragma unroll
    for (int ks = 0; ks < 4; ++ks)
        #pragma unroll
        for (int ml = 0; ml < 2; ++ml)
            #pragma unroll
            for (int nl = 0; nl < 4; ++nl)
                acc[ml][nl] = __builtin_amdgcn_mfma_f32_16x16x32_bf16(af[ml][ks], bf[nl][ks], acc[ml][nl], 0, 0, 0);

    #pragma unroll
    for (int ml = 0; ml < 2; ++ml) {
        int hid0 = wv*32 + ml*16 + quad*4;
        f32x4 b1v = *(const f32x4*)(b1 + e*128 + hid0);
        #pragma unroll
        for (int nl = 0; nl < 4; ++nl) {
            short4v hv;
            #pragma unroll
            for (int r = 0; r < 4; ++r) {
                float v = acc[ml][nl][r] + b1v[r];
                hv[r] = f2bf(fmaxf(v, 0.f));
            }
            *(short4v*)(hL + (nl*16 + l16) * PT + hid0) = hv;
        }
    }
    __syncthreads();

    // ---- GEMM2' ----
    f32x4 acc2[2];
    acc2[0] = (f32x4){0.f, 0.f, 0.f, 0.f};
    acc2[1] = (f32x4){0.f, 0.f, 0.f, 0.f};

    short8 af2[2][4];
    #pragma unroll
    for (int ml = 0; ml < 2; ++ml)
        #pragma unroll
        for (int ks = 0; ks < 4; ++ks)
            af2[ml][ks] = *(const short8*)(W2F + ((size_t)(((e*2 + ml)*4 + ks)*64 + lane)) * 8);

    short8 bf2[4];
    #pragma unroll
    for (int ks = 0; ks < 4; ++ks)
        bf2[ks] = *(const short8*)(hL + (wv*16 + l16) * PT + ks*32 + quad*8);

    #pragma unroll
    for (int ks = 0; ks < 4; ++ks)
        #pragma unroll
        for (int ml = 0; ml < 2; ++ml)
            acc2[ml] = __builtin_amdgcn_mfma_f32_16x16x32_bf16(af2[ml][ks], bf2[ks], acc2[ml], 0, 0, 0);

    // ---- fused head: partial = dot(o_token, Wout[h*32..]) over this lane's 8 od
    const int slot = wv*16 + l16;
    const int nn   = ids[slot];
    const int hsel = nn & 3;
    float partial = 0.f;
    #pragma unroll
    for (int ml = 0; ml < 2; ++ml) {
        int od0 = ml*16 + quad*4;
        f32x4 b2v = *(const f32x4*)(b2 + e*32 + od0);
        const float* wseg = WoutL + hsel*32 + od0;
        #pragma unroll
        for (int r = 0; r < 4; ++r)
            partial += (acc2[ml][r] + b2v[r]) * wseg[r];
    }
    // reduce across the 4 quads (same l16)
    partial += __shfl_xor(partial, 16);
    partial += __shfl_xor(partial, 32);
    if (quad == 0) {
        float v = partial * wsl[slot];
        atomicAdd(&out[nn >> 2], v);
    }
}

extern "C" void kernel_launch(void* const* d_in, const int* in_sizes, int n_in,
                              void* d_out, int out_size, void* d_ws, size_t ws_size,
                              hipStream_t stream) {
    (void)in_sizes; (void)n_in; (void)out_size; (void)ws_size;
    const float* x    = (const float*)d_in[0];
    const float* Wq   = (const float*)d_in[1];
    const float* bq   = (const float*)d_in[2];
    const float* Wk   = (const float*)d_in[3];
    const float* bk   = (const float*)d_in[4];
    const float* Wg   = (const float*)d_in[5];
    const float* W1   = (const float*)d_in[6];
    const float* b1   = (const float*)d_in[7];
    const float* W2   = (const float*)d_in[8];
    const float* b2   = (const float*)d_in[9];
    const float* Wout = (const float*)d_in[10];
    const float* bout = (const float*)d_in[11];
    float* out = (float*)d_out;

    char* ws = (char*)d_ws;
    short* tokb     = (short*)(ws + 0);              // 16,777,216
    int*   topi     = (int*)  (ws + 16777216);       //    524,288
    float* wts      = (float*)(ws + 17301504);       //    524,288
    int*   listIdx  = (int*)  (ws + 17825792);       //    526,336
    short* WqF      = (short*)(ws + 18352128);       //    131,072
    short* W1F      = (short*)(ws + 18483200);       //    262,144
    short* W2F      = (short*)(ws + 18745344);       //     65,536
    float* Wkg      = (float*)(ws + 18810880);       //     16,384
    float* bkg      = (float*)(ws + 18827264);       //        128
    float* blkPart  = (float*)(ws + 18827392);       //     32,768
    int*   bases    = (int*)  (ws + 18860160);       //         32
    int*   cursors  = (int*)  (ws + 18860192);       //         32
    int*   assignCnt= (int*)  (ws + 18860224);       //         32

    prep<<<977, 256, 0, stream>>>(Wq, Wk, Wg, bk, W1, W2, bout, WqF, W1F, W2F, Wkg, bkg, out);
    k1q_tok<<<512, 256, 0, stream>>>(x, WqF, bq, tokb);
    k1_gate<<<256, 256, 0, stream>>>(x, Wkg, bkg, topi, wts, blkPart);
    k2s_scan<<<1, 256, 0, stream>>>(blkPart, bases, cursors, assignCnt, out);
    k2a_bin<<<256, 256, 0, stream>>>(topi, cursors, listIdx);
    k2b_expert<<<dim3(1024, 8), 256, 0, stream>>>(tokb, W1F, b1, W2F, b2, assignCnt, bases, listIdx, wts, Wout, out);
}